// Round 8
// baseline (545.234 us; speedup 1.0000x reference)
//
#include <hip/hip_runtime.h>
#include <cstdint>

#define Nn 50000
#define Ee 800000
#define NBLK 196              // ceil(Nn/256)
#define ND4 (Nn*64/4)         // 800000 16B-groups in an N*64 array
#define NDTOT ((size_t)Nn * 64)
#define NGB 782               // ceil(Nn/64) gemm blocks

__device__ __forceinline__ float relu_f(float v){ return v > 0.f ? v : 0.f; }

// bf16 <-> fp32 (RNE round)
__device__ __forceinline__ unsigned short f2bf(float f){
    unsigned u = __float_as_uint(f);
    u += 0x7fffu + ((u >> 16) & 1u);
    return (unsigned short)(u >> 16);
}
__device__ __forceinline__ float bf2f(unsigned short s){
    return __uint_as_float((unsigned)s << 16);
}
// accumulate 8 packed bf16 (uint4) into fp32[8]
__device__ __forceinline__ void add_bf8(float* a, uint4 u){
    a[0] += __uint_as_float(u.x << 16);
    a[1] += __uint_as_float(u.x & 0xffff0000u);
    a[2] += __uint_as_float(u.y << 16);
    a[3] += __uint_as_float(u.y & 0xffff0000u);
    a[4] += __uint_as_float(u.z << 16);
    a[5] += __uint_as_float(u.z & 0xffff0000u);
    a[6] += __uint_as_float(u.w << 16);
    a[7] += __uint_as_float(u.w & 0xffff0000u);
}
// branch-free row index: clamp e for a safe csr load, select zero-row (Nn) if OOB
__device__ __forceinline__ int rowidx(unsigned e, unsigned end, const unsigned* __restrict__ csr){
    unsigned ec = e < (Ee - 1u) ? e : (Ee - 1u);
    int idx = (int)csr[ec];
    return (e < end) ? idx : Nn;
}

__global__ __launch_bounds__(256) void k_degree(const int* __restrict__ src, const int* __restrict__ dst,
                                                unsigned* __restrict__ dout, unsigned* __restrict__ din){
    int e = blockIdx.x * 256 + threadIdx.x;
    if (e < Ee){
        atomicAdd(&dout[src[e]], 1u);
        atomicAdd(&din[dst[e]], 1u);
    }
}

// ---- block sums of deg_in (for scan) + norms fused ----
__global__ __launch_bounds__(256) void k_blocksum(const unsigned* __restrict__ din, const unsigned* __restrict__ dout,
                                                  unsigned* __restrict__ bsum,
                                                  float* __restrict__ ns, float* __restrict__ nd){
    __shared__ unsigned s[256];
    int t = threadIdx.x; int i = blockIdx.x * 256 + t;
    unsigned v = (i < Nn) ? din[i] : 0u;
    s[t] = v;
    if (i < Nn){
        ns[i] = rsqrtf((float)(dout[i] + 1u));   // +1 = self loop
        nd[i] = rsqrtf((float)(v + 1u));
    }
    __syncthreads();
    for (int off = 128; off > 0; off >>= 1){ if (t < off) s[t] += s[t + off]; __syncthreads(); }
    if (t == 0) bsum[blockIdx.x] = s[0];
}

__global__ __launch_bounds__(256) void k_scanblocks(const unsigned* __restrict__ bsum, unsigned* __restrict__ boff,
                                                    unsigned* __restrict__ offsets){
    __shared__ unsigned s[256];
    int t = threadIdx.x;
    unsigned v = (t < NBLK) ? bsum[t] : 0u;
    s[t] = v; __syncthreads();
    for (int off = 1; off < 256; off <<= 1){
        unsigned add = (t >= off) ? s[t - off] : 0u;
        __syncthreads();
        s[t] += add;
        __syncthreads();
    }
    boff[t] = s[t] - v;
    if (t == 255) offsets[Nn] = s[255];
}

__global__ __launch_bounds__(256) void k_offsets(const unsigned* __restrict__ din, const unsigned* __restrict__ boff,
                                                 unsigned* __restrict__ offsets, unsigned* __restrict__ cursor){
    __shared__ unsigned s[256];
    int t = threadIdx.x; int i = blockIdx.x * 256 + t;
    unsigned v = (i < Nn) ? din[i] : 0u;
    s[t] = v; __syncthreads();
    for (int off = 1; off < 256; off <<= 1){
        unsigned add = (t >= off) ? s[t - off] : 0u;
        __syncthreads();
        s[t] += add;
        __syncthreads();
    }
    if (i < Nn){
        unsigned val = s[t] - v + boff[blockIdx.x];
        offsets[i] = val;
        cursor[i]  = val;
    }
}

__global__ __launch_bounds__(256) void k_fillcsr(const int* __restrict__ src, const int* __restrict__ dst,
                                                 unsigned* __restrict__ cursor, unsigned* __restrict__ csr){
    int e = blockIdx.x * 256 + threadIdx.x;
    if (e < Ee){
        unsigned pos = atomicAdd(&cursor[dst[e]], 1u);
        csr[pos] = (unsigned)src[e];
    }
}

// ---- h0 = bf16(F * norm_src); last block zeroes row Nn of BOTH h buffers ----
__global__ __launch_bounds__(256) void k_h0(const float* __restrict__ x, const float* __restrict__ ns,
                                            unsigned short* __restrict__ hA, unsigned short* __restrict__ hB){
    int i = blockIdx.x * 256 + threadIdx.x;
    if (i < ND4){
        const float4* x4 = (const float4*)x;
        float s = ns[i >> 4];
        float4 v = x4[i];
        ushort4 o;
        o.x = f2bf(v.x * s); o.y = f2bf(v.y * s);
        o.z = f2bf(v.z * s); o.w = f2bf(v.w * s);
        ((ushort4*)hA)[i] = o;
    } else {
        int j = i - ND4;
        if (j < 16){
            ushort4 z = make_ushort4(0, 0, 0, 0);
            ((ushort4*)hA)[ND4 + j] = z;
            ((ushort4*)hB)[ND4 + j] = z;
        }
    }
}

// ---- SpMM gather (R7 branch-free 32-edge burst), agg output now bf16 ----
__global__ __launch_bounds__(256) void k_gather(const unsigned short* __restrict__ h,
                                                const unsigned* __restrict__ offsets,
                                                const unsigned* __restrict__ csr, const float* __restrict__ nd,
                                                unsigned short* __restrict__ agg){
    int v = blockIdx.x * 4 + (threadIdx.x >> 6);
    int lane = threadIdx.x & 63;
    int slot = lane >> 3;
    int sub  = lane & 7;
    const uint4* h16 = (const uint4*)h;

    unsigned beg = offsets[v], end = offsets[v + 1];
    unsigned e0 = beg + slot;

    int i0 = rowidx(e0,      end, csr);
    int i1 = rowidx(e0 + 8,  end, csr);
    int i2 = rowidx(e0 + 16, end, csr);
    int i3 = rowidx(e0 + 24, end, csr);
    uint4 u0 = h16[(size_t)i0 * 8 + sub];
    uint4 u1 = h16[(size_t)i1 * 8 + sub];
    uint4 u2 = h16[(size_t)i2 * 8 + sub];
    uint4 u3 = h16[(size_t)i3 * 8 + sub];

    float acc[8];
    #pragma unroll
    for (int i = 0; i < 8; i++) acc[i] = 0.f;
    if (slot == 0) add_bf8(acc, h16[(size_t)v * 8 + sub]);   // self loop
    add_bf8(acc, u0);
    add_bf8(acc, u1);
    add_bf8(acc, u2);
    add_bf8(acc, u3);

    for (unsigned e = e0 + 32; e < end; e += 8){              // rare tail deg>32
        add_bf8(acc, h16[(size_t)((int)csr[e]) * 8 + sub]);
    }

    #pragma unroll
    for (int i = 0; i < 8; i++) acc[i] += __shfl_xor(acc[i], 8, 64);
    #pragma unroll
    for (int i = 0; i < 8; i++) acc[i] += __shfl_xor(acc[i], 16, 64);
    #pragma unroll
    for (int i = 0; i < 8; i++) acc[i] += __shfl_xor(acc[i], 32, 64);

    if (slot == 0){
        float s = nd[v];
        ushort4 o0, o1;
        o0.x = f2bf(acc[0] * s); o0.y = f2bf(acc[1] * s);
        o0.z = f2bf(acc[2] * s); o0.w = f2bf(acc[3] * s);
        o1.x = f2bf(acc[4] * s); o1.y = f2bf(acc[5] * s);
        o1.z = f2bf(acc[6] * s); o1.w = f2bf(acc[7] * s);
        ushort4* aggp = (ushort4*)agg;
        aggp[(size_t)v * 16 + sub * 2 + 0] = o0;
        aggp[(size_t)v * 16 + sub * 2 + 1] = o1;
    }
}

// ---- layers 0,1: y = relu(agg@W + b), out = bf16(y*ns) ----
__global__ __launch_bounds__(256) void k_gemm(const unsigned short* __restrict__ agg, const float* __restrict__ W,
                                              const float* __restrict__ bias, const float* __restrict__ ns,
                                              unsigned short* __restrict__ xout){
    __shared__ float As[64 * 65];
    __shared__ float Ws[64 * 64];
    int t = threadIdx.x;
    int m_base = blockIdx.x * 64;
    const float4* W4  = (const float4*)W;
    float4* Ws4       = (float4*)Ws;
    const ushort4* a4 = (const ushort4*)agg;
    #pragma unroll
    for (int i = 0; i < 4; i++){
        int g = t + 256 * i;
        Ws4[g] = W4[g];
        int m = g >> 4, q = g & 15;
        int node = m_base + m;
        ushort4 u = make_ushort4(0, 0, 0, 0);
        if (node < Nn) u = a4[(size_t)node * 16 + q];
        float* dp = &As[m * 65 + q * 4];
        dp[0] = bf2f(u.x); dp[1] = bf2f(u.y); dp[2] = bf2f(u.z); dp[3] = bf2f(u.w);
    }
    __syncthreads();
    int tm = t >> 4, tn = t & 15;
    float acc[4][4];
    #pragma unroll
    for (int i = 0; i < 4; i++)
        #pragma unroll
        for (int j = 0; j < 4; j++) acc[i][j] = 0.f;
    #pragma unroll 4
    for (int k = 0; k < 64; k++){
        float4 w = *(const float4*)&Ws[k * 64 + tn * 4];
        float a[4];
        #pragma unroll
        for (int i = 0; i < 4; i++) a[i] = As[(tm * 4 + i) * 65 + k];
        #pragma unroll
        for (int i = 0; i < 4; i++){
            acc[i][0] += a[i] * w.x;
            acc[i][1] += a[i] * w.y;
            acc[i][2] += a[i] * w.z;
            acc[i][3] += a[i] * w.w;
        }
    }
    float4 b4 = ((const float4*)bias)[tn];
    #pragma unroll
    for (int i = 0; i < 4; i++){
        int node = m_base + tm * 4 + i;
        if (node < Nn){
            float s = ns[node];
            ushort4 o;
            o.x = f2bf(relu_f(acc[i][0] + b4.x) * s);
            o.y = f2bf(relu_f(acc[i][1] + b4.y) * s);
            o.z = f2bf(relu_f(acc[i][2] + b4.z) * s);
            o.w = f2bf(relu_f(acc[i][3] + b4.w) * s);
            ((ushort4*)xout)[(size_t)node * 16 + tn] = o;
        }
    }
}

// ---- layer 2 GEMM + fc fused: y tile stays in registers; block consumes its
// 256KB fc_w slice (coalesced stream, overlaps compute) -> 16 partials/block. ----
__global__ __launch_bounds__(256) void k_gemm2fc(const unsigned short* __restrict__ agg, const float* __restrict__ W,
                                                 const float* __restrict__ bias, const float* __restrict__ fcw,
                                                 float* __restrict__ partials){
    __shared__ float As[64 * 65];
    __shared__ float Ws[64 * 64];   // reused as 16x256 reduce buffer after GEMM
    int t = threadIdx.x;
    int m_base = blockIdx.x * 64;
    const float4* W4  = (const float4*)W;
    float4* Ws4       = (float4*)Ws;
    const ushort4* a4 = (const ushort4*)agg;
    #pragma unroll
    for (int i = 0; i < 4; i++){
        int g = t + 256 * i;
        Ws4[g] = W4[g];
        int m = g >> 4, q = g & 15;
        int node = m_base + m;
        ushort4 u = make_ushort4(0, 0, 0, 0);
        if (node < Nn) u = a4[(size_t)node * 16 + q];
        float* dp = &As[m * 65 + q * 4];
        dp[0] = bf2f(u.x); dp[1] = bf2f(u.y); dp[2] = bf2f(u.z); dp[3] = bf2f(u.w);
    }
    __syncthreads();
    int tm = t >> 4, tn = t & 15;
    float acc[4][4];
    #pragma unroll
    for (int i = 0; i < 4; i++)
        #pragma unroll
        for (int j = 0; j < 4; j++) acc[i][j] = 0.f;
    #pragma unroll 4
    for (int k = 0; k < 64; k++){
        float4 w = *(const float4*)&Ws[k * 64 + tn * 4];
        float a[4];
        #pragma unroll
        for (int i = 0; i < 4; i++) a[i] = As[(tm * 4 + i) * 65 + k];
        #pragma unroll
        for (int i = 0; i < 4; i++){
            acc[i][0] += a[i] * w.x;
            acc[i][1] += a[i] * w.y;
            acc[i][2] += a[i] * w.z;
            acc[i][3] += a[i] * w.w;
        }
    }
    float4 b4 = ((const float4*)bias)[tn];
    // relu in place (y never goes to global)
    #pragma unroll
    for (int i = 0; i < 4; i++){
        acc[i][0] = relu_f(acc[i][0] + b4.x);
        acc[i][1] = relu_f(acc[i][1] + b4.y);
        acc[i][2] = relu_f(acc[i][2] + b4.z);
        acc[i][3] = relu_f(acc[i][3] + b4.w);
    }
    // fc partials: p[o] = sum_i,j acc[i][j] * fcw[o][node_i*64 + tn*4+j]
    const float4* fw4 = (const float4*)fcw;
    float p[16];
    #pragma unroll
    for (int o = 0; o < 16; o++){
        float s = 0.f;
        #pragma unroll
        for (int i = 0; i < 4; i++){
            int node = m_base + tm * 4 + i;
            int nc = node < Nn ? node : (Nn - 1);             // clamp address
            float4 w = fw4[(size_t)o * ND4 + (size_t)nc * 16 + tn];
            float m = (node < Nn) ? 1.f : 0.f;                // mask tail nodes
            s += m * (acc[i][0] * w.x + acc[i][1] * w.y + acc[i][2] * w.z + acc[i][3] * w.w);
        }
        p[o] = s;
    }
    __syncthreads();               // everyone done reading Ws -> reuse
    #pragma unroll
    for (int o = 0; o < 16; o++) Ws[o * 256 + t] = p[o];
    __syncthreads();
    int o = t >> 4, i2 = t & 15;
    float s = 0.f;
    #pragma unroll
    for (int m = 0; m < 16; m++) s += Ws[o * 256 + m * 16 + i2];
    s += __shfl_down(s, 8, 64);
    s += __shfl_down(s, 4, 64);
    s += __shfl_down(s, 2, 64);
    s += __shfl_down(s, 1, 64);
    if (i2 == 0) partials[blockIdx.x * 16 + o] = s;
}

// ---- final reduce: NGB x 16 -> 16 (+bias) ----
__global__ __launch_bounds__(256) void k_fc2(const float* __restrict__ partials, const float* __restrict__ fcb,
                                             float* __restrict__ out){
    __shared__ float red[256];
    int t = threadIdx.x; int o = t & 15, rr = t >> 4;
    float s = 0.f;
    for (int r = rr; r < NGB; r += 16) s += partials[r * 16 + o];
    red[t] = s; __syncthreads();
    for (int off = 128; off >= 16; off >>= 1){ if (t < off) red[t] += red[t + off]; __syncthreads(); }
    if (t < 16) out[t] = red[t] + fcb[t];
}

extern "C" void kernel_launch(void* const* d_in, const int* in_sizes, int n_in,
                              void* d_out, int out_size, void* d_ws, size_t ws_size,
                              hipStream_t stream) {
    const float* F     = (const float*)d_in[0];
    const int*   src   = (const int*)d_in[1];
    const int*   dst   = (const int*)d_in[2];
    const float* gcn_w = (const float*)d_in[3];
    const float* gcn_b = (const float*)d_in[4];
    const float* fc_w  = (const float*)d_in[5];
    const float* fc_b  = (const float*)d_in[6];
    float* out = (float*)d_out;

    char* wsp = (char*)d_ws;
    auto alloc = [&](size_t bytes) -> char* {
        char* p = wsp;
        wsp += (bytes + 255) & ~size_t(255);
        return p;
    };
    unsigned* deg      = (unsigned*)alloc(2 * Nn * 4);
    unsigned* deg_out_ = deg;
    unsigned* deg_in_  = deg + Nn;
    unsigned* offsets  = (unsigned*)alloc((Nn + 1) * 4);
    unsigned* cursor   = (unsigned*)alloc(Nn * 4);
    unsigned* bsum     = (unsigned*)alloc(256 * 4);
    unsigned* boff     = (unsigned*)alloc(256 * 4);
    unsigned* csr      = (unsigned*)alloc(Ee * 4);
    float* norm_src    = (float*)alloc(Nn * 4);
    float* norm_dst    = (float*)alloc(Nn * 4);
    float* partials    = (float*)alloc(NGB * 16 * 4);
    unsigned short* hA = (unsigned short*)alloc((NDTOT + 64) * 2);   // +zero row
    unsigned short* hB = (unsigned short*)alloc((NDTOT + 64) * 2);
    unsigned short* aggb = (unsigned short*)alloc(NDTOT * 2);        // bf16 agg

    hipMemsetAsync(deg, 0, 2 * Nn * 4, stream);

    k_degree<<<Ee / 256, 256, 0, stream>>>(src, dst, deg_out_, deg_in_);
    k_blocksum<<<NBLK, 256, 0, stream>>>(deg_in_, deg_out_, bsum, norm_src, norm_dst);
    k_scanblocks<<<1, 256, 0, stream>>>(bsum, boff, offsets);
    k_offsets<<<NBLK, 256, 0, stream>>>(deg_in_, boff, offsets, cursor);
    k_fillcsr<<<Ee / 256, 256, 0, stream>>>(src, dst, cursor, csr);

    k_h0<<<ND4 / 256 + 1, 256, 0, stream>>>(F, norm_src, hA, hB);

    // L0: hA -> agg -> hB; L1: hB -> agg -> hA; L2: hA -> agg -> fc partials
    k_gather<<<Nn / 4, 256, 0, stream>>>(hA, offsets, csr, norm_dst, aggb);
    k_gemm<<<NGB, 256, 0, stream>>>(aggb, gcn_w + 0 * 4096, gcn_b + 0 * 64, norm_src, hB);
    k_gather<<<Nn / 4, 256, 0, stream>>>(hB, offsets, csr, norm_dst, aggb);
    k_gemm<<<NGB, 256, 0, stream>>>(aggb, gcn_w + 1 * 4096, gcn_b + 1 * 64, norm_src, hA);
    k_gather<<<Nn / 4, 256, 0, stream>>>(hA, offsets, csr, norm_dst, aggb);
    k_gemm2fc<<<NGB, 256, 0, stream>>>(aggb, gcn_w + 2 * 4096, gcn_b + 2 * 64, fc_w, partials);

    k_fc2<<<1, 256, 0, stream>>>(partials, fc_b, out);
}